// Round 19
// baseline (133.083 us; speedup 1.0000x reference)
//
#include <hip/hip_runtime.h>
#include <math.h>

#define FDIM 64
#define HDIM 128
#define CLSD 64

#define NPART 8             // dst partitions ~ XCDs
#define MAXDEG 64           // ELL row stride; P(deg>=64)~1e-55 for Poisson(16)

typedef unsigned short ushort_t;
typedef _Float16 hfrag __attribute__((ext_vector_type(8)));   // 8 fp16 (4 VGPRs)
typedef float f32x4 __attribute__((ext_vector_type(4)));

#define LOG2E 1.4426950408889634f

__device__ __forceinline__ float ex2(float x){ float r; asm("v_exp_f32 %0, %1" : "=v"(r) : "v"(x)); return r; }
__device__ __forceinline__ float rcp_(float x){ float r; asm("v_rcp_f32 %0, %1" : "=v"(r) : "v"(x)); return r; }
__device__ __forceinline__ float fsigmoid(float x){ return rcp_(1.0f + ex2(-LOG2E*x)); }
__device__ __forceinline__ float ftanh(float x){ return 1.0f - 2.0f*rcp_(1.0f + ex2(2.0f*LOG2E*x)); }

__device__ __forceinline__ ushort_t f2h(float f){
    _Float16 h = (_Float16)f;
    ushort_t u; __builtin_memcpy(&u, &h, 2); return u;
}
__device__ __forceinline__ float hflo(unsigned int u){
    ushort_t v = (ushort_t)u; _Float16 h; __builtin_memcpy(&h, &v, 2); return (float)h;
}
__device__ __forceinline__ float hfhi(unsigned int u){
    ushort_t v = (ushort_t)(u >> 16); _Float16 h; __builtin_memcpy(&h, &v, 2); return (float)h;
}
__device__ __forceinline__ unsigned int pk2h(float a, float b){
    return (unsigned int)f2h(a) | ((unsigned int)f2h(b) << 16);
}

// Ab fragment layout: ((ntile*6 + s)*64 + lane) int4; row = ntile*16 + (lane&15),
// k = s*32 + ((lane>>4)&3)*8 + elem. s=0..1 = G (gather); s=2..5 = h1 (k_preX).
// Bh layout: ((s*32 + T)*64 + lane) int4 — wave's 8 T-tiles contiguous per K-step.

// ---------------- prep A: weight fold + pack + bsum + cnt=0 ----------------
// __launch_bounds__(256) REQUIRED (r7 bug: default bound caps VGPR at 64 -> spill).
__launch_bounds__(256)
__global__ void k_preW(const float* __restrict__ Wg, const float* __restrict__ bg,
                       const float* __restrict__ Wx, const float* __restrict__ Th,
                       const float* __restrict__ Wl,
                       const float* __restrict__ bga, const float* __restrict__ bco,
                       ushort_t* __restrict__ Bh, ushort_t* __restrict__ Lh,
                       float* __restrict__ bsum, int* __restrict__ cnt, int N){
    int tid = blockIdx.x*256 + threadIdx.x;
    if (tid < 98304){                       // B = [W'=Wg@Wx ; Th], 192 x 512 -> fp16
        int k = tid >> 9, col = tid & 511;
        float v;
        if (k < 64){
            float acc = 0.f;
            #pragma unroll 8
            for (int f = 0; f < 64; ++f) acc += Wg[k*64 + f]*Wx[f*512 + col];
            v = acc;
        } else {
            v = Th[(k-64)*512 + col];
        }
        int g = col >> 7, hc = col & 127;
        int w = hc >> 5, within = hc & 31;
        int c8 = g*2 + (within >> 4);
        int T = w*8 + c8;
        int s = k >> 5;
        int lane = ((k >> 3) & 3)*16 + (within & 15);
        int pos = ((s*32 + T)*64 + lane)*8 + (k & 7);    // [s][T][lane] layout
        Bh[pos] = f2h(v);
    } else if (tid < 106496){               // 128 x 64 Wlin -> fp16
        int i = tid - 98304;
        int k = i >> 6, col = i & 63;
        float v = Wl[k*64 + col];
        int ct = col >> 4;
        int s = k >> 5;
        int lane = ((k >> 3) & 3)*16 + (col & 15);
        int pos = ((ct*4 + s)*64 + lane)*8 + (k & 7);
        Lh[pos] = f2h(v);
    } else if (tid < 107008){               // bsum = bga + bco + b_gcn @ Wx
        int c = tid - 106496;
        float acc = bga[c] + bco[c];
        #pragma unroll 8
        for (int f = 0; f < 64; ++f) acc += bg[f]*Wx[f*512 + c];
        bsum[c] = acc;
    } else if (tid - 107008 < N){           // cnt = 0
        cnt[tid - 107008] = 0;
    }
}

// ---------------- prep B: pure streaming — xh cast + h1->Ab pack + oh1 ----------
__launch_bounds__(256)
__global__ void k_preX(const float* __restrict__ x, const float* __restrict__ h1,
                       ushort_t* __restrict__ xh, ushort_t* __restrict__ Ab,
                       float* __restrict__ oh1, int N, int N2){
    int tid = blockIdx.x*256 + threadIdx.x;
    if (tid < N*8){                         // xh = fp16(x), 8 elems/thread
        const float4* xp = (const float4*)(x + (size_t)tid*8);
        float4 p0 = xp[0], p1 = xp[1];
        ((int4*)xh)[tid] = make_int4((int)pk2h(p0.x,p0.y), (int)pk2h(p0.z,p0.w),
                                     (int)pk2h(p1.x,p1.y), (int)pk2h(p1.z,p1.w));
    } else {                                // h1 -> Ab rows [64,192) + oh1 passthrough
        int i = tid - N*8;                  // i in [0, N2*16)
        if (i >= N2*16) return;
        int n = i >> 4, q = i & 15;         // q: 8-col chunk of h1's 128 cols
        int4 frag = make_int4(0,0,0,0);
        if (n < N){
            const float4* src = (const float4*)(h1 + (size_t)n*128 + q*8);
            float4 p0 = src[0], p1 = src[1];
            float4* dst = (float4*)(oh1 + (size_t)n*128 + q*8);
            dst[0] = p0; dst[1] = p1;
            frag = make_int4((int)pk2h(p0.x,p0.y), (int)pk2h(p0.z,p0.w),
                             (int)pk2h(p1.x,p1.y), (int)pk2h(p1.z,p1.w));
        }
        int s = 2 + (q >> 2);
        int lane = (q & 3)*16 + (n & 15);
        ((int4*)Ab)[((size_t)(n >> 4)*6 + s)*64 + lane] = frag;
    }
}

// ELL bucket-fill (one edge pass), dst-partitioned (r12: XCD-local atomics).
__launch_bounds__(256)
__global__ void k_fill(const int* __restrict__ ei, int* __restrict__ cnt,
                       int* __restrict__ ell, int E, int psz){
    int p   = blockIdx.x % NPART;
    int bi  = blockIdx.x / NPART;
    int bpp = gridDim.x / NPART;
    int chunk = (E + bpp - 1) / bpp;
    int beg = bi*chunk;
    int end = beg + chunk; if (end > E) end = E;
    int lo = p*psz, hi = lo + psz;
    for (int i = beg + threadIdx.x; i < end; i += 256){
        int d = ei[E + i];
        if (d >= lo && d < hi){
            int s = ei[i];
            int slot = atomicAdd(&cnt[d], 1);
            if (slot < MAXDEG) ell[(size_t)d*MAXDEG + slot] = s;
        }
    }
}

// G gather -> Ab s=0..1; dinv inline from cnt; 8 lanes/node x 8 fp16 cols.
__launch_bounds__(256)
__global__ void k_gather(const int* __restrict__ cnt, const int* __restrict__ ell,
                         const ushort_t* __restrict__ xh,
                         ushort_t* __restrict__ Ab, int N, int N2){
    int tid = blockIdx.x*256 + threadIdx.x;
    int n = tid >> 3, q = tid & 7;
    if (n >= N2) return;
    int s_ = q >> 2;
    int lane = (q & 3)*16 + (n & 15);
    size_t fpos = ((size_t)(n >> 4)*6 + s_)*64 + lane;
    if (n >= N){
        ((int4*)Ab)[fpos] = make_int4(0,0,0,0);
        return;
    }
    int cn = cnt[n]; if (cn > MAXDEG) cn = MAXDEG;
    const int* row = ell + (size_t)n*MAXDEG;
    const int4* xv = (const int4*)xh;
    float a0=0.f,a1=0.f,a2=0.f,a3=0.f,a4=0.f,a5=0.f,a6=0.f,a7=0.f;
    int idx = 0;
    for (; idx + 4 <= cn; idx += 4){
        int s0 = row[idx], s1 = row[idx+1], s2 = row[idx+2], s3 = row[idx+3];
        float w0 = rsqrtf((float)cnt[s0] + 1.0f);
        float w1 = rsqrtf((float)cnt[s1] + 1.0f);
        float w2 = rsqrtf((float)cnt[s2] + 1.0f);
        float w3 = rsqrtf((float)cnt[s3] + 1.0f);
        int4 u = xv[(size_t)s0*8 + q];
        int4 p = xv[(size_t)s1*8 + q];
        int4 v = xv[(size_t)s2*8 + q];
        int4 z = xv[(size_t)s3*8 + q];
        a0 += w0*hflo((unsigned)u.x) + w1*hflo((unsigned)p.x) + w2*hflo((unsigned)v.x) + w3*hflo((unsigned)z.x);
        a1 += w0*hfhi((unsigned)u.x) + w1*hfhi((unsigned)p.x) + w2*hfhi((unsigned)v.x) + w3*hfhi((unsigned)z.x);
        a2 += w0*hflo((unsigned)u.y) + w1*hflo((unsigned)p.y) + w2*hflo((unsigned)v.y) + w3*hflo((unsigned)z.y);
        a3 += w0*hfhi((unsigned)u.y) + w1*hfhi((unsigned)p.y) + w2*hfhi((unsigned)v.y) + w3*hfhi((unsigned)z.y);
        a4 += w0*hflo((unsigned)u.z) + w1*hflo((unsigned)p.z) + w2*hflo((unsigned)v.z) + w3*hflo((unsigned)z.z);
        a5 += w0*hfhi((unsigned)u.z) + w1*hfhi((unsigned)p.z) + w2*hfhi((unsigned)v.z) + w3*hfhi((unsigned)z.z);
        a6 += w0*hflo((unsigned)u.w) + w1*hflo((unsigned)p.w) + w2*hflo((unsigned)v.w) + w3*hflo((unsigned)z.w);
        a7 += w0*hfhi((unsigned)u.w) + w1*hfhi((unsigned)p.w) + w2*hfhi((unsigned)v.w) + w3*hfhi((unsigned)z.w);
    }
    for (; idx < cn; ++idx){
        int s0 = row[idx];
        float w0 = rsqrtf((float)cnt[s0] + 1.0f);
        int4 u = xv[(size_t)s0*8 + q];
        a0 += w0*hflo((unsigned)u.x); a1 += w0*hfhi((unsigned)u.x);
        a2 += w0*hflo((unsigned)u.y); a3 += w0*hfhi((unsigned)u.y);
        a4 += w0*hflo((unsigned)u.z); a5 += w0*hfhi((unsigned)u.z);
        a6 += w0*hflo((unsigned)u.w); a7 += w0*hfhi((unsigned)u.w);
    }
    float dn = rsqrtf((float)cn + 1.0f);
    int4 sv = xv[(size_t)n*8 + q];
    a0 = dn*(a0 + dn*hflo((unsigned)sv.x));
    a1 = dn*(a1 + dn*hfhi((unsigned)sv.x));
    a2 = dn*(a2 + dn*hflo((unsigned)sv.y));
    a3 = dn*(a3 + dn*hfhi((unsigned)sv.y));
    a4 = dn*(a4 + dn*hflo((unsigned)sv.z));
    a5 = dn*(a5 + dn*hfhi((unsigned)sv.z));
    a6 = dn*(a6 + dn*hflo((unsigned)sv.w));
    a7 = dn*(a7 + dn*hfhi((unsigned)sv.w));
    ((int4*)Ab)[fpos] = make_int4((int)pk2h(a0,a1), (int)pk2h(a2,a3),
                                  (int)pk2h(a4,a5), (int)pk2h(a6,a7));
}

// ---------------- fused MFMA kernel: 64 nodes, 8 waves, h2 staged early -------
// T14 async-stage: h2 tile (64x128 f32, stride-132 pad) is loaded global->LDS at
// kernel entry; its HBM latency hides under the GEMM. LDS is time-shared:
// [h2 tile 33792B] during GEMM -> [Hh 16KB | Ltile 17KB] after.
__launch_bounds__(512)
__global__ void k_fused(const ushort_t* __restrict__ Ab, const float* __restrict__ h2,
                        const ushort_t* __restrict__ Bh, const ushort_t* __restrict__ Lh,
                        const float* __restrict__ bsum, const float* __restrict__ wc,
                        const float* __restrict__ blin,
                        float* __restrict__ outC, ushort_t* __restrict__ zb, int N)
{
    __shared__ __align__(16) char smem[33792];
    float*    h2s  = (float*)smem;              // [64][132] f32 = 33792 B (phase 1)
    ushort_t* Hh   = (ushort_t*)smem;           // [4 mh][4 sp][64] x16B = 16384 B (phase 2)
    float*    Ltile = (float*)(smem + 16384);   // [64][68] fp32 = 17408 B (phase 2)

    const int t    = threadIdx.x;
    const int w    = t >> 6;
    const int wm   = w >> 2;
    const int wn   = w & 3;
    const int lane = t & 63;
    const int nb   = blockIdx.x * 64;
    const size_t bt = (size_t)blockIdx.x * 4;

    // ---- stage h2 tile into LDS (issued before GEMM; latency hidden) ----
    {
        const float4* h2g = (const float4*)h2;
        #pragma unroll
        for (int i = 0; i < 4; ++i){
            int idx = i*512 + t;                // 0..2047
            int row = idx >> 5, c4 = idx & 31;
            int gr = nb + row;
            float4 v = (gr < N) ? h2g[(size_t)gr*32 + c4]
                                : make_float4(0.f,0.f,0.f,0.f);
            *(float4*)&h2s[row*132 + c4*4] = v;
        }
    }

    // ---- gates GEMM: K=192 (6 steps), named b0..b7, A prefetch ----
    f32x4 acc[2][8];
    #pragma unroll
    for (int mt = 0; mt < 2; ++mt)
        #pragma unroll
        for (int c8 = 0; c8 < 8; ++c8)
            acc[mt][c8] = (f32x4){0.f,0.f,0.f,0.f};

    const hfrag* AF  = (const hfrag*)Ab;
    const hfrag* BhF = (const hfrag*)Bh;

    const size_t aidx0 = (bt + wm*2 + 0)*384 + lane;
    const size_t aidx1 = (bt + wm*2 + 1)*384 + lane;
    const size_t bb    = (size_t)(wn*8)*64 + lane;

    hfrag a0 = AF[aidx0];
    hfrag a1 = AF[aidx1];
    #pragma unroll
    for (int s = 0; s < 6; ++s){
        size_t sb = (size_t)s*2048 + bb;
        hfrag b0 = BhF[sb +   0];
        hfrag b1 = BhF[sb +  64];
        hfrag b2 = BhF[sb + 128];
        hfrag b3 = BhF[sb + 192];
        hfrag b4 = BhF[sb + 256];
        hfrag b5 = BhF[sb + 320];
        hfrag b6 = BhF[sb + 384];
        hfrag b7 = BhF[sb + 448];
        hfrag a0n = a0, a1n = a1;
        if (s < 5){
            a0n = AF[aidx0 + (s+1)*64];
            a1n = AF[aidx1 + (s+1)*64];
        }
        acc[0][0] = __builtin_amdgcn_mfma_f32_16x16x32_f16(a0, b0, acc[0][0], 0,0,0);
        acc[1][0] = __builtin_amdgcn_mfma_f32_16x16x32_f16(a1, b0, acc[1][0], 0,0,0);
        acc[0][1] = __builtin_amdgcn_mfma_f32_16x16x32_f16(a0, b1, acc[0][1], 0,0,0);
        acc[1][1] = __builtin_amdgcn_mfma_f32_16x16x32_f16(a1, b1, acc[1][1], 0,0,0);
        acc[0][2] = __builtin_amdgcn_mfma_f32_16x16x32_f16(a0, b2, acc[0][2], 0,0,0);
        acc[1][2] = __builtin_amdgcn_mfma_f32_16x16x32_f16(a1, b2, acc[1][2], 0,0,0);
        acc[0][3] = __builtin_amdgcn_mfma_f32_16x16x32_f16(a0, b3, acc[0][3], 0,0,0);
        acc[1][3] = __builtin_amdgcn_mfma_f32_16x16x32_f16(a1, b3, acc[1][3], 0,0,0);
        acc[0][4] = __builtin_amdgcn_mfma_f32_16x16x32_f16(a0, b4, acc[0][4], 0,0,0);
        acc[1][4] = __builtin_amdgcn_mfma_f32_16x16x32_f16(a1, b4, acc[1][4], 0,0,0);
        acc[0][5] = __builtin_amdgcn_mfma_f32_16x16x32_f16(a0, b5, acc[0][5], 0,0,0);
        acc[1][5] = __builtin_amdgcn_mfma_f32_16x16x32_f16(a1, b5, acc[1][5], 0,0,0);
        acc[0][6] = __builtin_amdgcn_mfma_f32_16x16x32_f16(a0, b6, acc[0][6], 0,0,0);
        acc[1][6] = __builtin_amdgcn_mfma_f32_16x16x32_f16(a1, b6, acc[1][6], 0,0,0);
        acc[0][7] = __builtin_amdgcn_mfma_f32_16x16x32_f16(a0, b7, acc[0][7], 0,0,0);
        acc[1][7] = __builtin_amdgcn_mfma_f32_16x16x32_f16(a1, b7, acc[1][7], 0,0,0);
        a0 = a0n; a1 = a1n;
    }
    __syncthreads();                 // h2 tile fully staged

    // ---- pull this thread's 16 h2 values LDS -> regs ----
    float hv[2][2][4];
    #pragma unroll
    for (int hc_t = 0; hc_t < 2; ++hc_t){
        int hc = wn*32 + hc_t*16 + (lane & 15);
        #pragma unroll
        for (int mt = 0; mt < 2; ++mt)
            #pragma unroll
            for (int rr = 0; rr < 4; ++rr){
                int row = wm*32 + mt*16 + ((lane >> 4) & 3)*4 + rr;
                hv[hc_t][mt][rr] = h2s[row*132 + hc];
            }
    }
    __syncthreads();                 // safe to overwrite LDS with Hh/Ltile

    // ---- LSTM elementwise, in-register ----
    #pragma unroll
    for (int hc_t = 0; hc_t < 2; ++hc_t){
        int hc  = wn*32 + hc_t*16 + (lane & 15);
        float bi = bsum[hc],       bfv = bsum[128 + hc];
        float bc = bsum[256 + hc], bo  = bsum[384 + hc];
        float wci = wc[hc], wcf = wc[128 + hc], wco = wc[256 + hc];
        #pragma unroll
        for (int mt = 0; mt < 2; ++mt){
            #pragma unroll
            for (int rr = 0; rr < 4; ++rr){
                int row = wm*32 + mt*16 + ((lane >> 4) & 3)*4 + rr;
                int gr  = nb + row;
                float gi = acc[mt][0 + hc_t][rr] + bi;
                float gf = acc[mt][2 + hc_t][rr] + bfv;
                float gc = acc[mt][4 + hc_t][rr] + bc;
                float go = acc[mt][6 + hc_t][rr] + bo;
                float hvv = hv[hc_t][mt][rr];
                float I  = fsigmoid(gi + wci*hvv);
                float Fg = fsigmoid(gf + wcf*hvv);
                float C  = Fg*hvv + I*ftanh(gc);
                float O  = fsigmoid(go + wco*C);
                float hn = O*ftanh(C);
                if (gr < N) outC[(size_t)gr*128 + hc] = C;
                float hr = fmaxf(hn, 0.0f);
                int l2  = (row & 15) + (hc_t*2 + ((lane >> 3) & 1))*16;
                int pos = (((wm*2 + mt)*4 + wn)*64 + l2)*8 + (lane & 7);
                Hh[pos] = f2h(hr);
            }
        }
    }
    __syncthreads();

    // ---- logits GEMM: K=128 (4 sp); wave (wm,wn): rows wm*32+.., class tile wn ----
    const hfrag* HF  = (const hfrag*)Hh;
    const hfrag* LhF = (const hfrag*)Lh;
    f32x4 acc2[2];
    acc2[0] = (f32x4){0.f,0.f,0.f,0.f};
    acc2[1] = (f32x4){0.f,0.f,0.f,0.f};
    #pragma unroll
    for (int sp = 0; sp < 4; ++sp){
        hfrag a0l = HF[((wm*2+0)*4 + sp)*64 + lane];
        hfrag a1l = HF[((wm*2+1)*4 + sp)*64 + lane];
        hfrag bh  = LhF[(wn*4 + sp)*64 + lane];
        acc2[0] = __builtin_amdgcn_mfma_f32_16x16x32_f16(a0l, bh, acc2[0], 0,0,0);
        acc2[1] = __builtin_amdgcn_mfma_f32_16x16x32_f16(a1l, bh, acc2[1], 0,0,0);
    }
    {
        int cls = wn*16 + (lane & 15);
        float bv = blin[cls];
        #pragma unroll
        for (int mtl = 0; mtl < 2; ++mtl){
            #pragma unroll
            for (int rr = 0; rr < 4; ++rr){
                int row = wm*32 + mtl*16 + ((lane >> 4) & 3)*4 + rr;
                Ltile[row*68 + cls] = acc2[mtl][rr] + bv;
            }
        }
    }
    __syncthreads();

    // ---- softmax + fp16 z write: 8 threads per node ----
    {
        int m = t >> 3, q = t & 7;
        const float4* Lr = (const float4*)&Ltile[m*68 + q*8];
        float4 v0 = Lr[0], v1 = Lr[1];
        float mx = fmaxf(fmaxf(fmaxf(v0.x,v0.y),fmaxf(v0.z,v0.w)),
                         fmaxf(fmaxf(v1.x,v1.y),fmaxf(v1.z,v1.w)));
        #pragma unroll
        for (int off2 = 1; off2 < 8; off2 <<= 1) mx = fmaxf(mx, __shfl_xor(mx, off2, 64));
        float e[8];
        e[0]=ex2(LOG2E*(v0.x-mx)); e[1]=ex2(LOG2E*(v0.y-mx));
        e[2]=ex2(LOG2E*(v0.z-mx)); e[3]=ex2(LOG2E*(v0.w-mx));
        e[4]=ex2(LOG2E*(v1.x-mx)); e[5]=ex2(LOG2E*(v1.y-mx));
        e[6]=ex2(LOG2E*(v1.z-mx)); e[7]=ex2(LOG2E*(v1.w-mx));
        float s8 = e[0]+e[1]+e[2]+e[3]+e[4]+e[5]+e[6]+e[7];
        #pragma unroll
        for (int off2 = 1; off2 < 8; off2 <<= 1) s8 += __shfl_xor(s8, off2, 64);
        float inv = rcp_(s8);
        if (nb + m < N){
            ((int4*)zb)[(size_t)(nb+m)*8 + q] =
                make_int4((int)pk2h(e[0]*inv, e[1]*inv), (int)pk2h(e[2]*inv, e[3]*inv),
                          (int)pk2h(e[4]*inv, e[5]*inv), (int)pk2h(e[6]*inv, e[7]*inv));
        }
    }
}

// r[e] = dot64(z[src], z[dst]) on fp16 z; 8 lanes x 16B per edge
__launch_bounds__(256)
__global__ void k_dec(const int* __restrict__ eli, const ushort_t* __restrict__ zb,
                      float* __restrict__ r, int EL){
    int tid = blockIdx.x*256 + threadIdx.x;
    int e = tid >> 3, l = tid & 7;
    if (e >= EL) return;
    int s = eli[e], d = eli[EL + e];
    int4 a = ((const int4*)zb)[(size_t)s*8 + l];
    int4 b = ((const int4*)zb)[(size_t)d*8 + l];
    unsigned int ua[4] = {(unsigned)a.x,(unsigned)a.y,(unsigned)a.z,(unsigned)a.w};
    unsigned int ub[4] = {(unsigned)b.x,(unsigned)b.y,(unsigned)b.z,(unsigned)b.w};
    float p = 0.f;
    #pragma unroll
    for (int j = 0; j < 4; ++j){
        p += hflo(ua[j])*hflo(ub[j]) + hfhi(ua[j])*hfhi(ub[j]);
    }
    #pragma unroll
    for (int off = 1; off < 8; off <<= 1) p += __shfl_xor(p, off, 64);
    if (l == 0) r[e] = p;
}

extern "C" void kernel_launch(void* const* d_in, const int* in_sizes, int n_in,
                              void* d_out, int out_size, void* d_ws, size_t ws_size,
                              hipStream_t stream)
{
    const float* x   = (const float*)d_in[0];
    const int*   ei  = (const int*)  d_in[1];
    const int*   eli = (const int*)  d_in[2];
    const float* h1  = (const float*)d_in[3];
    const float* h2  = (const float*)d_in[4];
    const float* Wg  = (const float*)d_in[5];
    const float* bg  = (const float*)d_in[6];
    const float* Wx  = (const float*)d_in[7];
    const float* Th  = (const float*)d_in[8];
    const float* bga = (const float*)d_in[9];
    const float* bco = (const float*)d_in[10];
    const float* wc  = (const float*)d_in[11];
    const float* Wl  = (const float*)d_in[12];
    const float* bl  = (const float*)d_in[13];

    const int N  = in_sizes[0] / FDIM;
    const int E  = in_sizes[1] / 2;
    const int EL = in_sizes[2] / 2;
    const int N2 = (N + 63) & ~63;                       // padded to 64
    const int PSZ = (N + NPART - 1) / NPART;             // dst partition size

    // workspace: xh (N*64 fp16) | Ab (N2*192 fp16) | zb (N*64 fp16) | cnt | ell | weights
    float* ws   = (float*)d_ws;
    ushort_t* xh = (ushort_t*)ws;
    ushort_t* Ab = xh + (size_t)N*64;
    ushort_t* zb = Ab + (size_t)N2*192;
    int*   cnt  = (int*)(zb + (size_t)N*64);
    int*   ell  = cnt + N;
    size_t base = (size_t)((ell + (size_t)N*MAXDEG) - (int*)ws);
    base = (base + 3) & ~(size_t)3;              // 16B align
    ushort_t* Bh = (ushort_t*)(ws + base);       // 98304 fp16
    ushort_t* Lh = Bh + 98304;                   // 8192 fp16
    float*  bsum = (float*)(Lh + 8192);          // 512 f32

    float* out = (float*)d_out;
    float* r   = out;                            // [EL]
    float* oh1 = out + EL;                       // [N*128] passthrough (k_preX)
    float* oC  = out + EL + (size_t)N*HDIM;      // [N*128]

    const int epBlocks  = NPART * 256;           // fill: 2048 blocks
    const int pXthreads = N*8 + N2*16;
    const int pWthreads = 107008 + N;

    k_preW  <<<(pWthreads + 255)/256, 256, 0, stream>>>(Wg, bg, Wx, Th, Wl, bga, bco,
                                                        Bh, Lh, bsum, cnt, N);
    k_preX  <<<(pXthreads + 255)/256, 256, 0, stream>>>(x, h1, xh, Ab, oh1, N, N2);
    k_fill  <<<epBlocks, 256, 0, stream>>>(ei, cnt, ell, E, PSZ);
    k_gather<<<((size_t)N2*8 + 255)/256, 256, 0, stream>>>(cnt, ell, xh, Ab, N, N2);
    k_fused <<<N2/64, 512, 0, stream>>>(Ab, h2, Bh, Lh, bsum, wc, bl, oC, zb, N);
    k_dec   <<<(EL*8 + 255)/256, 256, 0, stream>>>(eli, zb, r, EL);
}

// Round 20
// 119.836 us; speedup vs baseline: 1.1105x; 1.1105x over previous
//
#include <hip/hip_runtime.h>
#include <math.h>

#define FDIM 64
#define HDIM 128
#define CLSD 64

#define NPART 8             // dst partitions ~ XCDs
#define MAXDEG 64           // ELL row stride; P(deg>=64)~1e-55 for Poisson(16)

typedef unsigned short ushort_t;
typedef _Float16 hfrag __attribute__((ext_vector_type(8)));   // 8 fp16 (4 VGPRs)
typedef float f32x4 __attribute__((ext_vector_type(4)));

#define LOG2E 1.4426950408889634f

__device__ __forceinline__ float ex2(float x){ float r; asm("v_exp_f32 %0, %1" : "=v"(r) : "v"(x)); return r; }
__device__ __forceinline__ float rcp_(float x){ float r; asm("v_rcp_f32 %0, %1" : "=v"(r) : "v"(x)); return r; }
__device__ __forceinline__ float fsigmoid(float x){ return rcp_(1.0f + ex2(-LOG2E*x)); }
__device__ __forceinline__ float ftanh(float x){ return 1.0f - 2.0f*rcp_(1.0f + ex2(2.0f*LOG2E*x)); }

__device__ __forceinline__ ushort_t f2h(float f){
    _Float16 h = (_Float16)f;
    ushort_t u; __builtin_memcpy(&u, &h, 2); return u;
}
__device__ __forceinline__ float hflo(unsigned int u){
    ushort_t v = (ushort_t)u; _Float16 h; __builtin_memcpy(&h, &v, 2); return (float)h;
}
__device__ __forceinline__ float hfhi(unsigned int u){
    ushort_t v = (ushort_t)(u >> 16); _Float16 h; __builtin_memcpy(&h, &v, 2); return (float)h;
}
__device__ __forceinline__ unsigned int pk2h(float a, float b){
    return (unsigned int)f2h(a) | ((unsigned int)f2h(b) << 16);
}

// Ab fragment layout: ((ntile*6 + s)*64 + lane) int4; row = ntile*16 + (lane&15),
// k = s*32 + ((lane>>4)&3)*8 + elem. s=0..1 = G (gather); s=2..5 = h1 (k_pre).
// Bh layout: ((s*32 + T)*64 + lane) int4 — wave's 8 T-tiles contiguous per K-step.

// ------- merged prep (r14 form): weights + bsum + cnt=0 + xh + h1->Ab + oh1 -------
// Flat tid-sections (each block homogeneous). NO loops (r15 lesson).
// __launch_bounds__(256) REQUIRED (r7 bug: default bound caps VGPR at 64 -> spill).
__launch_bounds__(256)
__global__ void k_pre(const float* __restrict__ x,  const float* __restrict__ Wg,
                      const float* __restrict__ bg,
                      const float* __restrict__ Wx, const float* __restrict__ Th,
                      const float* __restrict__ Wl,
                      const float* __restrict__ bga, const float* __restrict__ bco,
                      const float* __restrict__ h1,
                      ushort_t* __restrict__ Bh, ushort_t* __restrict__ Lh,
                      float* __restrict__ bsum, int* __restrict__ cnt,
                      ushort_t* __restrict__ xh, ushort_t* __restrict__ Ab,
                      float* __restrict__ oh1, int N, int N2){
    int tid = blockIdx.x*256 + threadIdx.x;
    const int secW = 107008 + N;            // weights + bsum + cnt
    const int secX = secW + N*8;            // xh cast
    if (tid < 98304){                       // B = [W'=Wg@Wx ; Th], 192 x 512 -> fp16
        int k = tid >> 9, col = tid & 511;
        float v;
        if (k < 64){
            float acc = 0.f;
            #pragma unroll 8
            for (int f = 0; f < 64; ++f) acc += Wg[k*64 + f]*Wx[f*512 + col];
            v = acc;
        } else {
            v = Th[(k-64)*512 + col];
        }
        int g = col >> 7, hc = col & 127;
        int w = hc >> 5, within = hc & 31;
        int c8 = g*2 + (within >> 4);
        int T = w*8 + c8;
        int s = k >> 5;
        int lane = ((k >> 3) & 3)*16 + (within & 15);
        int pos = ((s*32 + T)*64 + lane)*8 + (k & 7);    // [s][T][lane] layout
        Bh[pos] = f2h(v);
    } else if (tid < 106496){               // 128 x 64 Wlin -> fp16
        int i = tid - 98304;
        int k = i >> 6, col = i & 63;
        float v = Wl[k*64 + col];
        int ct = col >> 4;
        int s = k >> 5;
        int lane = ((k >> 3) & 3)*16 + (col & 15);
        int pos = ((ct*4 + s)*64 + lane)*8 + (k & 7);
        Lh[pos] = f2h(v);
    } else if (tid < 107008){               // bsum = bga + bco + b_gcn @ Wx
        int c = tid - 106496;
        float acc = bga[c] + bco[c];
        #pragma unroll 8
        for (int f = 0; f < 64; ++f) acc += bg[f]*Wx[f*512 + c];
        bsum[c] = acc;
    } else if (tid < secW){                 // cnt = 0
        cnt[tid - 107008] = 0;
    } else if (tid < secX){                 // xh = fp16(x), 8 elems/thread
        int i = tid - secW;
        const float4* xp = (const float4*)(x + (size_t)i*8);
        float4 p0 = xp[0], p1 = xp[1];
        ((int4*)xh)[i] = make_int4((int)pk2h(p0.x,p0.y), (int)pk2h(p0.z,p0.w),
                                   (int)pk2h(p1.x,p1.y), (int)pk2h(p1.z,p1.w));
    } else {                                // h1 -> Ab rows [64,192) + oh1 passthrough
        int i = tid - secX;                 // i in [0, N2*16)
        if (i >= N2*16) return;
        int n = i >> 4, q = i & 15;         // q: 8-col chunk of h1's 128 cols
        int4 frag = make_int4(0,0,0,0);
        if (n < N){
            const float4* src = (const float4*)(h1 + (size_t)n*128 + q*8);
            float4 p0 = src[0], p1 = src[1];
            float4* dst = (float4*)(oh1 + (size_t)n*128 + q*8);
            dst[0] = p0; dst[1] = p1;
            frag = make_int4((int)pk2h(p0.x,p0.y), (int)pk2h(p0.z,p0.w),
                             (int)pk2h(p1.x,p1.y), (int)pk2h(p1.z,p1.w));
        }
        int s = 2 + (q >> 2);
        int lane = (q & 3)*16 + (n & 15);
        ((int4*)Ab)[((size_t)(n >> 4)*6 + s)*64 + lane] = frag;
    }
}

// ELL bucket-fill (one edge pass), dst-partitioned (r12: XCD-local atomics).
__launch_bounds__(256)
__global__ void k_fill(const int* __restrict__ ei, int* __restrict__ cnt,
                       int* __restrict__ ell, int E, int psz){
    int p   = blockIdx.x % NPART;
    int bi  = blockIdx.x / NPART;
    int bpp = gridDim.x / NPART;
    int chunk = (E + bpp - 1) / bpp;
    int beg = bi*chunk;
    int end = beg + chunk; if (end > E) end = E;
    int lo = p*psz, hi = lo + psz;
    for (int i = beg + threadIdx.x; i < end; i += 256){
        int d = ei[E + i];
        if (d >= lo && d < hi){
            int s = ei[i];
            int slot = atomicAdd(&cnt[d], 1);
            if (slot < MAXDEG) ell[(size_t)d*MAXDEG + slot] = s;
        }
    }
}

// G gather -> Ab s=0..1; dinv inline from cnt; 8 lanes/node x 8 fp16 cols.
__launch_bounds__(256)
__global__ void k_gather(const int* __restrict__ cnt, const int* __restrict__ ell,
                         const ushort_t* __restrict__ xh,
                         ushort_t* __restrict__ Ab, int N, int N2){
    int tid = blockIdx.x*256 + threadIdx.x;
    int n = tid >> 3, q = tid & 7;
    if (n >= N2) return;
    int s_ = q >> 2;
    int lane = (q & 3)*16 + (n & 15);
    size_t fpos = ((size_t)(n >> 4)*6 + s_)*64 + lane;
    if (n >= N){
        ((int4*)Ab)[fpos] = make_int4(0,0,0,0);
        return;
    }
    int cn = cnt[n]; if (cn > MAXDEG) cn = MAXDEG;
    const int* row = ell + (size_t)n*MAXDEG;
    const int4* xv = (const int4*)xh;
    float a0=0.f,a1=0.f,a2=0.f,a3=0.f,a4=0.f,a5=0.f,a6=0.f,a7=0.f;
    int idx = 0;
    for (; idx + 4 <= cn; idx += 4){
        int s0 = row[idx], s1 = row[idx+1], s2 = row[idx+2], s3 = row[idx+3];
        float w0 = rsqrtf((float)cnt[s0] + 1.0f);
        float w1 = rsqrtf((float)cnt[s1] + 1.0f);
        float w2 = rsqrtf((float)cnt[s2] + 1.0f);
        float w3 = rsqrtf((float)cnt[s3] + 1.0f);
        int4 u = xv[(size_t)s0*8 + q];
        int4 p = xv[(size_t)s1*8 + q];
        int4 v = xv[(size_t)s2*8 + q];
        int4 z = xv[(size_t)s3*8 + q];
        a0 += w0*hflo((unsigned)u.x) + w1*hflo((unsigned)p.x) + w2*hflo((unsigned)v.x) + w3*hflo((unsigned)z.x);
        a1 += w0*hfhi((unsigned)u.x) + w1*hfhi((unsigned)p.x) + w2*hfhi((unsigned)v.x) + w3*hfhi((unsigned)z.x);
        a2 += w0*hflo((unsigned)u.y) + w1*hflo((unsigned)p.y) + w2*hflo((unsigned)v.y) + w3*hflo((unsigned)z.y);
        a3 += w0*hfhi((unsigned)u.y) + w1*hfhi((unsigned)p.y) + w2*hfhi((unsigned)v.y) + w3*hfhi((unsigned)z.y);
        a4 += w0*hflo((unsigned)u.z) + w1*hflo((unsigned)p.z) + w2*hflo((unsigned)v.z) + w3*hflo((unsigned)z.z);
        a5 += w0*hfhi((unsigned)u.z) + w1*hfhi((unsigned)p.z) + w2*hfhi((unsigned)v.z) + w3*hfhi((unsigned)z.z);
        a6 += w0*hflo((unsigned)u.w) + w1*hflo((unsigned)p.w) + w2*hflo((unsigned)v.w) + w3*hflo((unsigned)z.w);
        a7 += w0*hfhi((unsigned)u.w) + w1*hfhi((unsigned)p.w) + w2*hfhi((unsigned)v.w) + w3*hfhi((unsigned)z.w);
    }
    for (; idx < cn; ++idx){
        int s0 = row[idx];
        float w0 = rsqrtf((float)cnt[s0] + 1.0f);
        int4 u = xv[(size_t)s0*8 + q];
        a0 += w0*hflo((unsigned)u.x); a1 += w0*hfhi((unsigned)u.x);
        a2 += w0*hflo((unsigned)u.y); a3 += w0*hfhi((unsigned)u.y);
        a4 += w0*hflo((unsigned)u.z); a5 += w0*hfhi((unsigned)u.z);
        a6 += w0*hflo((unsigned)u.w); a7 += w0*hfhi((unsigned)u.w);
    }
    float dn = rsqrtf((float)cn + 1.0f);
    int4 sv = xv[(size_t)n*8 + q];
    a0 = dn*(a0 + dn*hflo((unsigned)sv.x));
    a1 = dn*(a1 + dn*hfhi((unsigned)sv.x));
    a2 = dn*(a2 + dn*hflo((unsigned)sv.y));
    a3 = dn*(a3 + dn*hfhi((unsigned)sv.y));
    a4 = dn*(a4 + dn*hflo((unsigned)sv.z));
    a5 = dn*(a5 + dn*hfhi((unsigned)sv.z));
    a6 = dn*(a6 + dn*hflo((unsigned)sv.w));
    a7 = dn*(a7 + dn*hfhi((unsigned)sv.w));
    ((int4*)Ab)[fpos] = make_int4((int)pk2h(a0,a1), (int)pk2h(a2,a3),
                                  (int)pk2h(a4,a5), (int)pk2h(a6,a7));
}

// ---------------- fused MFMA kernel (r18 form — best measured) ----------------
__launch_bounds__(512)
__global__ void k_fused(const ushort_t* __restrict__ Ab, const float* __restrict__ h2,
                        const ushort_t* __restrict__ Bh, const ushort_t* __restrict__ Lh,
                        const float* __restrict__ bsum, const float* __restrict__ wc,
                        const float* __restrict__ blin,
                        float* __restrict__ outC, ushort_t* __restrict__ zb, int N)
{
    __shared__ __align__(16) char smem[33792];
    ushort_t* Hh   = (ushort_t*)smem;           // [4 mh][4 sp][64] x16B = 16384 B
    float*    Ltile = (float*)(smem + 16384);   // [64][68] fp32 = 17408 B

    const int t    = threadIdx.x;
    const int w    = t >> 6;
    const int wm   = w >> 2;
    const int wn   = w & 3;
    const int lane = t & 63;
    const int nb   = blockIdx.x * 64;
    const size_t bt = (size_t)blockIdx.x * 4;

    f32x4 acc[2][8];
    #pragma unroll
    for (int mt = 0; mt < 2; ++mt)
        #pragma unroll
        for (int c8 = 0; c8 < 8; ++c8)
            acc[mt][c8] = (f32x4){0.f,0.f,0.f,0.f};

    const hfrag* AF  = (const hfrag*)Ab;
    const hfrag* BhF = (const hfrag*)Bh;

    const size_t aidx0 = (bt + wm*2 + 0)*384 + lane;
    const size_t aidx1 = (bt + wm*2 + 1)*384 + lane;
    const size_t bb    = (size_t)(wn*8)*64 + lane;

    hfrag a0 = AF[aidx0];
    hfrag a1 = AF[aidx1];
    #pragma unroll
    for (int s = 0; s < 6; ++s){
        size_t sb = (size_t)s*2048 + bb;
        hfrag b0 = BhF[sb +   0];
        hfrag b1 = BhF[sb +  64];
        hfrag b2 = BhF[sb + 128];
        hfrag b3 = BhF[sb + 192];
        hfrag b4 = BhF[sb + 256];
        hfrag b5 = BhF[sb + 320];
        hfrag b6 = BhF[sb + 384];
        hfrag b7 = BhF[sb + 448];
        hfrag a0n = a0, a1n = a1;
        if (s < 5){
            a0n = AF[aidx0 + (s+1)*64];
            a1n = AF[aidx1 + (s+1)*64];
        }
        acc[0][0] = __builtin_amdgcn_mfma_f32_16x16x32_f16(a0, b0, acc[0][0], 0,0,0);
        acc[1][0] = __builtin_amdgcn_mfma_f32_16x16x32_f16(a1, b0, acc[1][0], 0,0,0);
        acc[0][1] = __builtin_amdgcn_mfma_f32_16x16x32_f16(a0, b1, acc[0][1], 0,0,0);
        acc[1][1] = __builtin_amdgcn_mfma_f32_16x16x32_f16(a1, b1, acc[1][1], 0,0,0);
        acc[0][2] = __builtin_amdgcn_mfma_f32_16x16x32_f16(a0, b2, acc[0][2], 0,0,0);
        acc[1][2] = __builtin_amdgcn_mfma_f32_16x16x32_f16(a1, b2, acc[1][2], 0,0,0);
        acc[0][3] = __builtin_amdgcn_mfma_f32_16x16x32_f16(a0, b3, acc[0][3], 0,0,0);
        acc[1][3] = __builtin_amdgcn_mfma_f32_16x16x32_f16(a1, b3, acc[1][3], 0,0,0);
        acc[0][4] = __builtin_amdgcn_mfma_f32_16x16x32_f16(a0, b4, acc[0][4], 0,0,0);
        acc[1][4] = __builtin_amdgcn_mfma_f32_16x16x32_f16(a1, b4, acc[1][4], 0,0,0);
        acc[0][5] = __builtin_amdgcn_mfma_f32_16x16x32_f16(a0, b5, acc[0][5], 0,0,0);
        acc[1][5] = __builtin_amdgcn_mfma_f32_16x16x32_f16(a1, b5, acc[1][5], 0,0,0);
        acc[0][6] = __builtin_amdgcn_mfma_f32_16x16x32_f16(a0, b6, acc[0][6], 0,0,0);
        acc[1][6] = __builtin_amdgcn_mfma_f32_16x16x32_f16(a1, b6, acc[1][6], 0,0,0);
        acc[0][7] = __builtin_amdgcn_mfma_f32_16x16x32_f16(a0, b7, acc[0][7], 0,0,0);
        acc[1][7] = __builtin_amdgcn_mfma_f32_16x16x32_f16(a1, b7, acc[1][7], 0,0,0);
        a0 = a0n; a1 = a1n;
    }

    // ---- LSTM elementwise, in-register ----
    #pragma unroll
    for (int hc_t = 0; hc_t < 2; ++hc_t){
        int hc  = wn*32 + hc_t*16 + (lane & 15);
        float bi = bsum[hc],       bfv = bsum[128 + hc];
        float bc = bsum[256 + hc], bo  = bsum[384 + hc];
        float wci = wc[hc], wcf = wc[128 + hc], wco = wc[256 + hc];
        #pragma unroll
        for (int mt = 0; mt < 2; ++mt){
            #pragma unroll
            for (int rr = 0; rr < 4; ++rr){
                int row = wm*32 + mt*16 + ((lane >> 4) & 3)*4 + rr;
                int gr  = nb + row;
                float gi = acc[mt][0 + hc_t][rr] + bi;
                float gf = acc[mt][2 + hc_t][rr] + bfv;
                float gc = acc[mt][4 + hc_t][rr] + bc;
                float go = acc[mt][6 + hc_t][rr] + bo;
                float hv = (gr < N) ? h2[(size_t)gr*128 + hc] : 0.0f;
                float I  = fsigmoid(gi + wci*hv);
                float Fg = fsigmoid(gf + wcf*hv);
                float C  = Fg*hv + I*ftanh(gc);
                float O  = fsigmoid(go + wco*C);
                float hn = O*ftanh(C);
                if (gr < N) outC[(size_t)gr*128 + hc] = C;
                float hr = fmaxf(hn, 0.0f);
                int l2  = (row & 15) + (hc_t*2 + ((lane >> 3) & 1))*16;
                int pos = (((wm*2 + mt)*4 + wn)*64 + l2)*8 + (lane & 7);
                Hh[pos] = f2h(hr);
            }
        }
    }
    __syncthreads();

    // ---- logits GEMM: K=128 (4 sp); wave (wm,wn): rows wm*32+.., class tile wn ----
    const hfrag* HF  = (const hfrag*)Hh;
    const hfrag* LhF = (const hfrag*)Lh;
    f32x4 acc2[2];
    acc2[0] = (f32x4){0.f,0.f,0.f,0.f};
    acc2[1] = (f32x4){0.f,0.f,0.f,0.f};
    #pragma unroll
    for (int sp = 0; sp < 4; ++sp){
        hfrag a0l = HF[((wm*2+0)*4 + sp)*64 + lane];
        hfrag a1l = HF[((wm*2+1)*4 + sp)*64 + lane];
        hfrag bh  = LhF[(wn*4 + sp)*64 + lane];
        acc2[0] = __builtin_amdgcn_mfma_f32_16x16x32_f16(a0l, bh, acc2[0], 0,0,0);
        acc2[1] = __builtin_amdgcn_mfma_f32_16x16x32_f16(a1l, bh, acc2[1], 0,0,0);
    }
    {
        int cls = wn*16 + (lane & 15);
        float bv = blin[cls];
        #pragma unroll
        for (int mtl = 0; mtl < 2; ++mtl){
            #pragma unroll
            for (int rr = 0; rr < 4; ++rr){
                int row = wm*32 + mtl*16 + ((lane >> 4) & 3)*4 + rr;
                Ltile[row*68 + cls] = acc2[mtl][rr] + bv;
            }
        }
    }
    __syncthreads();

    // ---- softmax + fp16 z write: 8 threads per node ----
    {
        int m = t >> 3, q = t & 7;
        const float4* Lr = (const float4*)&Ltile[m*68 + q*8];
        float4 v0 = Lr[0], v1 = Lr[1];
        float mx = fmaxf(fmaxf(fmaxf(v0.x,v0.y),fmaxf(v0.z,v0.w)),
                         fmaxf(fmaxf(v1.x,v1.y),fmaxf(v1.z,v1.w)));
        #pragma unroll
        for (int off2 = 1; off2 < 8; off2 <<= 1) mx = fmaxf(mx, __shfl_xor(mx, off2, 64));
        float e[8];
        e[0]=ex2(LOG2E*(v0.x-mx)); e[1]=ex2(LOG2E*(v0.y-mx));
        e[2]=ex2(LOG2E*(v0.z-mx)); e[3]=ex2(LOG2E*(v0.w-mx));
        e[4]=ex2(LOG2E*(v1.x-mx)); e[5]=ex2(LOG2E*(v1.y-mx));
        e[6]=ex2(LOG2E*(v1.z-mx)); e[7]=ex2(LOG2E*(v1.w-mx));
        float s8 = e[0]+e[1]+e[2]+e[3]+e[4]+e[5]+e[6]+e[7];
        #pragma unroll
        for (int off2 = 1; off2 < 8; off2 <<= 1) s8 += __shfl_xor(s8, off2, 64);
        float inv = rcp_(s8);
        if (nb + m < N){
            ((int4*)zb)[(size_t)(nb+m)*8 + q] =
                make_int4((int)pk2h(e[0]*inv, e[1]*inv), (int)pk2h(e[2]*inv, e[3]*inv),
                          (int)pk2h(e[4]*inv, e[5]*inv), (int)pk2h(e[6]*inv, e[7]*inv));
        }
    }
}

// r[e] = dot64(z[src], z[dst]) on fp16 z; 8 lanes x 16B per edge
__launch_bounds__(256)
__global__ void k_dec(const int* __restrict__ eli, const ushort_t* __restrict__ zb,
                      float* __restrict__ r, int EL){
    int tid = blockIdx.x*256 + threadIdx.x;
    int e = tid >> 3, l = tid & 7;
    if (e >= EL) return;
    int s = eli[e], d = eli[EL + e];
    int4 a = ((const int4*)zb)[(size_t)s*8 + l];
    int4 b = ((const int4*)zb)[(size_t)d*8 + l];
    unsigned int ua[4] = {(unsigned)a.x,(unsigned)a.y,(unsigned)a.z,(unsigned)a.w};
    unsigned int ub[4] = {(unsigned)b.x,(unsigned)b.y,(unsigned)b.z,(unsigned)b.w};
    float p = 0.f;
    #pragma unroll
    for (int j = 0; j < 4; ++j){
        p += hflo(ua[j])*hflo(ub[j]) + hfhi(ua[j])*hfhi(ub[j]);
    }
    #pragma unroll
    for (int off = 1; off < 8; off <<= 1) p += __shfl_xor(p, off, 64);
    if (l == 0) r[e] = p;
}

extern "C" void kernel_launch(void* const* d_in, const int* in_sizes, int n_in,
                              void* d_out, int out_size, void* d_ws, size_t ws_size,
                              hipStream_t stream)
{
    const float* x   = (const float*)d_in[0];
    const int*   ei  = (const int*)  d_in[1];
    const int*   eli = (const int*)  d_in[2];
    const float* h1  = (const float*)d_in[3];
    const float* h2  = (const float*)d_in[4];
    const float* Wg  = (const float*)d_in[5];
    const float* bg  = (const float*)d_in[6];
    const float* Wx  = (const float*)d_in[7];
    const float* Th  = (const float*)d_in[8];
    const float* bga = (const float*)d_in[9];
    const float* bco = (const float*)d_in[10];
    const float* wc  = (const float*)d_in[11];
    const float* Wl  = (const float*)d_in[12];
    const float* bl  = (const float*)d_in[13];

    const int N  = in_sizes[0] / FDIM;
    const int E  = in_sizes[1] / 2;
    const int EL = in_sizes[2] / 2;
    const int N2 = (N + 63) & ~63;                       // padded to 64
    const int PSZ = (N + NPART - 1) / NPART;             // dst partition size

    // workspace: xh (N*64 fp16) | Ab (N2*192 fp16) | zb (N*64 fp16) | cnt | ell | weights
    float* ws   = (float*)d_ws;
    ushort_t* xh = (ushort_t*)ws;
    ushort_t* Ab = xh + (size_t)N*64;
    ushort_t* zb = Ab + (size_t)N2*192;
    int*   cnt  = (int*)(zb + (size_t)N*64);
    int*   ell  = cnt + N;
    size_t base = (size_t)((ell + (size_t)N*MAXDEG) - (int*)ws);
    base = (base + 3) & ~(size_t)3;              // 16B align
    ushort_t* Bh = (ushort_t*)(ws + base);       // 98304 fp16
    ushort_t* Lh = Bh + 98304;                   // 8192 fp16
    float*  bsum = (float*)(Lh + 8192);          // 512 f32

    float* out = (float*)d_out;
    float* r   = out;                            // [EL]
    float* oh1 = out + EL;                       // [N*128] passthrough (k_pre)
    float* oC  = out + EL + (size_t)N*HDIM;      // [N*128]

    const int epBlocks   = NPART * 256;          // fill: 2048 blocks
    const int preThreads = 107008 + N + N*8 + N2*16;

    k_pre   <<<(preThreads + 255)/256, 256, 0, stream>>>(x, Wg, bg, Wx, Th, Wl, bga, bco,
                                                         h1, Bh, Lh, bsum, cnt,
                                                         xh, Ab, oh1, N, N2);
    k_fill  <<<epBlocks, 256, 0, stream>>>(ei, cnt, ell, E, PSZ);
    k_gather<<<((size_t)N2*8 + 255)/256, 256, 0, stream>>>(cnt, ell, xh, Ab, N, N2);
    k_fused <<<N2/64, 512, 0, stream>>>(Ab, h2, Bh, Lh, bsum, wc, bl, oC, zb, N);
    k_dec   <<<(EL*8 + 255)/256, 256, 0, stream>>>(eli, zb, r, EL);
}